// Round 1
// baseline (232.858 us; speedup 1.0000x reference)
//
#include <hip/hip_runtime.h>
#include <cstdint>

#define EXPERTS 64
#define TOPK 8
#define ROWS_PER_BLOCK 256
#define CHUNK 16                 // columns staged per round
#define NCHUNK (EXPERTS / CHUNK) // 4
#define LDS_PITCH 17             // +1 pad -> owner reads are 2-way (free)

// order-preserving map f32 -> u32
__device__ __forceinline__ uint32_t mono32(float x) {
    int32_t b = __float_as_int(x);
    return (uint32_t)(b ^ ((b >> 31) | 0x80000000));
}

__global__ __launch_bounds__(256, 3)
void gumbel_topk_softmax_kernel(const float* __restrict__ gin,
                                const float* __restrict__ gnz,
                                float* __restrict__ gout) {
    __shared__ float ldsA[ROWS_PER_BLOCK * LDS_PITCH];
    __shared__ float ldsB[ROWS_PER_BLOCK * LDS_PITCH];

    const int t = threadIdx.x;
    const int rowbase = blockIdx.x * ROWS_PER_BLOCK;

    float vin[EXPERTS];      // own row's original inputs (static-indexed only)
    uint64_t heap[TOPK];     // top-8 keys, descending; key embeds (s, e, idx)
#pragma unroll
    for (int q = 0; q < TOPK; ++q) heap[q] = 0ull;

    const float4* gin4 = (const float4*)gin;
    const float4* gnz4 = (const float4*)gnz;

#pragma unroll
    for (int c = 0; c < NCHUNK; ++c) {
        // ---- cooperative coalesced load of a 256-row x 16-col chunk ----
        // 1024 float4 per array; lane pattern: 64B contiguous per row-piece
#pragma unroll
        for (int k = 0; k < 4; ++k) {
            int q = k * 256 + t;
            int r = q >> 2, f = q & 3;
            int g4 = (rowbase + r) * (EXPERTS / 4) + c * 4 + f;
            float4 a = gin4[g4];
            float4 b = gnz4[g4];
            int la = r * LDS_PITCH + 4 * f;
            ldsA[la + 0] = a.x; ldsA[la + 1] = a.y; ldsA[la + 2] = a.z; ldsA[la + 3] = a.w;
            ldsB[la + 0] = b.x; ldsB[la + 1] = b.y; ldsB[la + 2] = b.z; ldsB[la + 3] = b.w;
        }
        __syncthreads();
        // ---- owner phase: thread t consumes its own row t ----
#pragma unroll
        for (int e = 0; e < CHUNK; ++e) {
            const int j = c * CHUNK + e;
            float a = ldsA[t * LDS_PITCH + e];   // input
            float b = ldsB[t * LDS_PITCH + e];   // noise
            vin[j] = a;
            // exact sum via Knuth 2Sum: z = s + res exactly (matches f64 order)
            float s  = a + b;
            float ap = s - b;
            float bp = s - ap;
            float res = (a - ap) + (b - bp);
            uint32_t us = mono32(s);
            uint32_t ue = mono32(res);
            // key: [s:32 | e(top26):26 | (63-j):6]  -> desc value, asc index
            uint64_t key = ((uint64_t)us << 32) |
                           ((uint64_t)(ue >> 6) << 6) |
                           (uint64_t)(63 - j);
            // branchless sorted insert (descending). Reads OLD heap[q-1]: q runs 7..1.
#pragma unroll
            for (int q = TOPK - 1; q >= 1; --q) {
                uint64_t kept = (key > heap[q]) ? key : heap[q];
                heap[q] = (key > heap[q - 1]) ? heap[q - 1] : kept;
            }
            heap[0] = (key > heap[0]) ? key : heap[0];
        }
        __syncthreads();
    }

    // ---- selection mask from embedded indices ----
    uint64_t mask = 0ull;
#pragma unroll
    for (int q = 0; q < TOPK; ++q) {
        int j = 63 - (int)(heap[q] & 63ull);
        mask |= (1ull << j);
    }

    // ---- softmax over selected ORIGINAL inputs ----
    float m = -3.402823466e38f;
#pragma unroll
    for (int j = 0; j < EXPERTS; ++j) {
        if ((mask >> j) & 1ull) m = fmaxf(m, vin[j]);
    }
    float ssum = 0.f;
#pragma unroll
    for (int j = 0; j < EXPERTS; ++j) {
        float ev = ((mask >> j) & 1ull) ? __expf(vin[j] - m) : 0.0f;
        ssum += ev;
        vin[j] = ev;
    }
    const float inv = 1.0f / ssum;

    // ---- output: stage own row back through LDS, store coalesced ----
    float4* gout4 = (float4*)gout;
#pragma unroll
    for (int c = 0; c < NCHUNK; ++c) {
#pragma unroll
        for (int e = 0; e < CHUNK; ++e) {
            ldsA[t * LDS_PITCH + e] = vin[c * CHUNK + e] * inv;
        }
        __syncthreads();
#pragma unroll
        for (int k = 0; k < 4; ++k) {
            int q = k * 256 + t;
            int r = q >> 2, f = q & 3;
            int la = r * LDS_PITCH + 4 * f;
            float4 v;
            v.x = ldsA[la + 0]; v.y = ldsA[la + 1];
            v.z = ldsA[la + 2]; v.w = ldsA[la + 3];
            gout4[(rowbase + r) * (EXPERTS / 4) + c * 4 + f] = v;
        }
        __syncthreads();
    }
}

extern "C" void kernel_launch(void* const* d_in, const int* in_sizes, int n_in,
                              void* d_out, int out_size, void* d_ws, size_t ws_size,
                              hipStream_t stream) {
    const float* gin = (const float*)d_in[0];
    const float* gnz = (const float*)d_in[1];
    float* gout = (float*)d_out;
    const int nrows = in_sizes[0] / EXPERTS;      // 1,048,576
    const int grid = nrows / ROWS_PER_BLOCK;      // 4096
    gumbel_topk_softmax_kernel<<<grid, ROWS_PER_BLOCK, 0, stream>>>(gin, gnz, gout);
}

// Round 2
// 191.566 us; speedup vs baseline: 1.2156x; 1.2156x over previous
//
#include <hip/hip_runtime.h>
#include <cstdint>

#define EXPERTS 64
#define ROWS 256                 // rows per block (= block size, 1 thread/row)

typedef float float4v __attribute__((ext_vector_type(4)));

__device__ __forceinline__ uint32_t mono32(float x) {
    int32_t b = __float_as_int(x);
    return (uint32_t)(b ^ ((b >> 31) | 0x80000000));
}

// async global->LDS, 16B per lane; LDS dest = wave-uniform base + lane*16
__device__ __forceinline__ void gll16(const float* g, float* l) {
    __builtin_amdgcn_global_load_lds((const __attribute__((address_space(1))) void*)g,
                                     (__attribute__((address_space(3))) void*)l, 16, 0, 0);
}

__global__ __launch_bounds__(256, 3)
void gumbel_topk_softmax_kernel(const float* __restrict__ gin,
                                const float* __restrict__ gnz,
                                float* __restrict__ gout) {
    // linear LDS, one 256-row x 16-col chunk per array. Unit = 16B (4 floats).
    // physical unit u holds (row r = u>>2, slot p = u&3); logical col-quad
    // e4 = p ^ ((r>>1)&3)  -> owner b128 reads are bank-conflict-free.
    __shared__ __align__(16) float bufA[ROWS * 16];
    __shared__ __align__(16) float bufB[ROWS * 16];

    const int t    = threadIdx.x;
    const int wid  = t >> 6;
    const int row0 = blockIdx.x * ROWS;
    const int sw   = (t >> 1) & 3;

    // loader geometry: k-th quarter of the 256-unit chunk space
    int r_[4], e4_[4];
#pragma unroll
    for (int k = 0; k < 4; ++k) {
        int u = k * 256 + t;
        int r = u >> 2, p = u & 3;
        r_[k]  = r;
        e4_[k] = p ^ ((r >> 1) & 3);
    }

    // issue one chunk's staging: 8 x global_load_lds (4 per array)
    auto issue = [&](int c) {
#pragma unroll
        for (int k = 0; k < 4; ++k) {
            uint32_t gofs = (uint32_t)(row0 + r_[k]) * 64u + (uint32_t)c * 16u
                          + (uint32_t)e4_[k] * 4u;
            gll16(gin + gofs, &bufA[k * 1024 + wid * 256]);
            gll16(gnz + gofs, &bufB[k * 1024 + wid * 256]);
        }
    };

    float vin[EXPERTS];    // original inputs (static-indexed registers only)
    float keys[EXPERTS];   // z = in + noise (f32)
    float heap[8];         // top-8 z values, descending
#pragma unroll
    for (int q = 0; q < 8; ++q) heap[q] = -INFINITY;

    issue(0);
#pragma unroll
    for (int c = 0; c < 4; ++c) {
        __syncthreads();                       // gll(c) landed (implicit vmcnt0)
        float4v a4[4], b4[4];
#pragma unroll
        for (int e4 = 0; e4 < 4; ++e4) {
            int p = e4 ^ sw;
            a4[e4] = *(const float4v*)&bufA[t * 16 + p * 4];
            b4[e4] = *(const float4v*)&bufB[t * 16 + p * 4];
        }
        __syncthreads();                       // all waves' reads done
        if (c < 3) issue(c + 1);               // prefetch flies under compute
#pragma unroll
        for (int e4 = 0; e4 < 4; ++e4)
#pragma unroll
            for (int i = 0; i < 4; ++i) {
                const int j = c * 16 + e4 * 4 + i;
                float a = a4[e4][i];
                float s = a + b4[e4][i];
                vin[j]  = a;
                keys[j] = s;
                // min/max bubble: 2 ops/slot, keeps heap sorted desc
#pragma unroll
                for (int q = 0; q < 8; ++q) {
                    float h = heap[q];
                    heap[q] = fmaxf(h, s);
                    s       = fminf(h, s);
                }
            }
    }

    // ---- selection: fast path = threshold at T, exact when unique ----
    const float T = heap[7];
    int cnt = 0;
    uint32_t mlo = 0u, mhi = 0u;
#pragma unroll
    for (int j = 0; j < 64; ++j) {
        bool ge = keys[j] >= T;
        cnt += ge ? 1 : 0;
        if (j < 32) mlo |= ge ? (1u << j) : 0u;
        else        mhi |= ge ? (1u << (j - 32)) : 0u;
    }
    if (cnt != 8) {
        // cold (~3e-5 of rows): duplicate z at the boundary. Exact round-1
        // semantics: u64 key = [mono(s) | mono(res)>>6 | 63-j], 2Sum residual.
        unsigned long long h8[8];
#pragma unroll
        for (int q = 0; q < 8; ++q) h8[q] = 0ull;
        const float* brow = gnz + (size_t)(row0 + t) * 64;
#pragma unroll
        for (int j = 0; j < 64; ++j) {
            float a = vin[j], b = brow[j];
            float s  = a + b;
            float ap = s - b;
            float bp = s - ap;
            float res = (a - ap) + (b - bp);
            unsigned long long key = ((unsigned long long)mono32(s) << 32)
                                   | ((unsigned long long)(mono32(res) >> 6) << 6)
                                   | (unsigned long long)(63 - j);
#pragma unroll
            for (int q = 0; q < 8; ++q) {
                unsigned long long hq = h8[q];
                unsigned long long mx = key > hq ? key : hq;
                key   = key > hq ? hq : key;
                h8[q] = mx;
            }
        }
        mlo = mhi = 0u;
#pragma unroll
        for (int q = 0; q < 8; ++q) {
            int j = 63 - (int)(h8[q] & 63ull);
            if (j < 32) mlo |= 1u << j;
            else        mhi |= 1u << (j - 32);
        }
    }

    // ---- softmax over selected ORIGINAL inputs (no max-shift: |in|<6) ----
    float ssum = 0.f;
#pragma unroll
    for (int j = 0; j < 64; ++j) {
        uint32_t bit = (j < 32 ? (mlo >> j) : (mhi >> (j - 32))) & 1u;
        float ev = __expf(vin[j]) * (float)bit;
        ssum += ev;
        vin[j] = ev;
    }
    const float inv = 1.0f / ssum;

    // ---- output: swizzled owner writes, linear reads, coalesced stores ----
#pragma unroll
    for (int rnd = 0; rnd < 2; ++rnd) {
        const int c0 = rnd * 2, c1 = rnd * 2 + 1;
#pragma unroll
        for (int e4 = 0; e4 < 4; ++e4) {
            int p = e4 ^ sw;
            float4v va, vb;
#pragma unroll
            for (int i = 0; i < 4; ++i) {
                va[i] = vin[c0 * 16 + e4 * 4 + i] * inv;
                vb[i] = vin[c1 * 16 + e4 * 4 + i] * inv;
            }
            *(float4v*)&bufA[t * 16 + p * 4] = va;
            *(float4v*)&bufB[t * 16 + p * 4] = vb;
        }
        __syncthreads();
#pragma unroll
        for (int k = 0; k < 4; ++k) {
            float4v va = *(const float4v*)&bufA[k * 1024 + t * 4];
            float4v vb = *(const float4v*)&bufB[k * 1024 + t * 4];
            uint32_t g0 = (uint32_t)(row0 + r_[k]) * 64u + (uint32_t)c0 * 16u
                        + (uint32_t)e4_[k] * 4u;
            uint32_t g1 = (uint32_t)(row0 + r_[k]) * 64u + (uint32_t)c1 * 16u
                        + (uint32_t)e4_[k] * 4u;
            *(float4v*)(gout + g0) = va;
            *(float4v*)(gout + g1) = vb;
        }
        if (rnd == 0) __syncthreads();
    }
}

extern "C" void kernel_launch(void* const* d_in, const int* in_sizes, int n_in,
                              void* d_out, int out_size, void* d_ws, size_t ws_size,
                              hipStream_t stream) {
    const float* gin = (const float*)d_in[0];
    const float* gnz = (const float*)d_in[1];
    float* gout = (float*)d_out;
    const int nrows = in_sizes[0] / EXPERTS;   // 1,048,576
    const int grid  = nrows / ROWS;            // 4096
    gumbel_topk_softmax_kernel<<<grid, ROWS, 0, stream>>>(gin, gnz, gout);
}

// Round 3
// 153.978 us; speedup vs baseline: 1.5123x; 1.2441x over previous
//
#include <hip/hip_runtime.h>
#include <cstdint>

#define EXPERTS 64

typedef float float4v __attribute__((ext_vector_type(4)));

__device__ __forceinline__ uint32_t mono32(float x) {
    int32_t b = __float_as_int(x);
    return (uint32_t)(b ^ ((b >> 31) | 0x80000000));
}

// async global->LDS, 16B/lane; LDS dest = wave-uniform base + lane*16
__device__ __forceinline__ void gll16(const float* g, float* l) {
    __builtin_amdgcn_global_load_lds((const __attribute__((address_space(1))) void*)g,
                                     (__attribute__((address_space(3))) void*)l, 16, 0, 0);
}

// One wave per block, one thread per row, 64 rows staged whole.
// LDS map: physical 16B unit p = k*64+lane holds (row = p>>4, quad = (p&15)^(row&7)).
//  - gll instr k: per-lane global source = contiguous 1KB (rows 4k..4k+3) -> coalesced
//  - owner read:  thread t, quad q -> p = 16t + (q^(t&7)) -> 32-bank uniform (no conflict)
__global__ __launch_bounds__(64, 2)
void gumbel_topk_softmax_kernel(const float* __restrict__ gin,
                                const float* __restrict__ gnz,
                                float* __restrict__ gout) {
    __shared__ __align__(16) float bufA[64 * 64];   // inputs tile
    __shared__ __align__(16) float bufB[64 * 64];   // noise tile

    const int t    = threadIdx.x;        // 0..63 = local row
    const int row0 = blockIdx.x * 64;
    const int sw   = t & 7;

    // ---- stage everything: 32 x global_load_lds, one drain, zero barriers ----
#pragma unroll
    for (int k = 0; k < 16; ++k) {
        const int p = k * 64 + t;
        const int r = p >> 4;
        const int j = (p & 15) ^ (r & 7);
        const uint32_t gofs = (uint32_t)(row0 + r) * 64u + (uint32_t)j * 4u;
        gll16(gin + gofs, &bufA[k * 256]);
        gll16(gnz + gofs, &bufB[k * 256]);
    }
    __syncthreads();    // single wave: this is just the vmcnt(0) drain

    // ---- consume own row: bubble top-8 on z = in + noise ----
    float vin[EXPERTS];     // original inputs (static-indexed)
    float keys[EXPERTS];    // z values (static-indexed)
    float heap[8];
#pragma unroll
    for (int q = 0; q < 8; ++q) heap[q] = -INFINITY;

#pragma unroll
    for (int q = 0; q < 16; ++q) {
        const int p = 16 * t + (q ^ sw);
        float4v a = *(const float4v*)&bufA[p * 4];
        float4v b = *(const float4v*)&bufB[p * 4];
#pragma unroll
        for (int i = 0; i < 4; ++i) {
            const int j = q * 4 + i;
            float s = a[i] + b[i];
            vin[j]  = a[i];
            keys[j] = s;
#pragma unroll
            for (int u = 0; u < 8; ++u) {
                float h = heap[u];
                heap[u] = fmaxf(h, s);
                s       = fminf(h, s);
            }
        }
    }

    // ---- selection: threshold fast path, exact u64 fallback on ties ----
    const float T = heap[7];
    int cnt = 0;
    uint32_t mlo = 0u, mhi = 0u;
#pragma unroll
    for (int j = 0; j < 64; ++j) {
        bool ge = keys[j] >= T;
        cnt += ge ? 1 : 0;
        if (j < 32) mlo |= ge ? (1u << j) : 0u;
        else        mhi |= ge ? (1u << (j - 32)) : 0u;
    }
    if (cnt != 8) {
        // cold (~3e-5 of rows): duplicate z at rank-8 boundary. Exact order:
        // u64 key = [mono(s) | mono(2Sum residual)>>6 | 63-j]; noise from LDS.
        unsigned long long h8[8];
#pragma unroll
        for (int q = 0; q < 8; ++q) h8[q] = 0ull;
#pragma unroll
        for (int j = 0; j < 64; ++j) {
            const int p = 16 * t + ((j >> 2) ^ sw);
            float a = vin[j];
            float b = bufB[p * 4 + (j & 3)];
            float s  = a + b;
            float ap = s - b;
            float bp = s - ap;
            float res = (a - ap) + (b - bp);
            unsigned long long key = ((unsigned long long)mono32(s) << 32)
                                   | ((unsigned long long)(mono32(res) >> 6) << 6)
                                   | (unsigned long long)(63 - j);
#pragma unroll
            for (int q = 0; q < 8; ++q) {
                unsigned long long hq = h8[q];
                unsigned long long mx = key > hq ? key : hq;
                key   = key > hq ? hq : key;
                h8[q] = mx;
            }
        }
        mlo = mhi = 0u;
#pragma unroll
        for (int q = 0; q < 8; ++q) {
            int j = 63 - (int)(h8[q] & 63ull);
            if (j < 32) mlo |= 1u << j;
            else        mhi |= 1u << (j - 32);
        }
    }

    // ---- softmax over selected ORIGINAL inputs (no shift: |in| small) ----
    float ssum = 0.f;
#pragma unroll
    for (int j = 0; j < 64; ++j) {
        uint32_t bit = (j < 32 ? (mlo >> j) : (mhi >> (j - 32))) & 1u;
        float ev = __expf(vin[j]) * (float)bit;
        ssum += ev;
        vin[j] = ev;
    }
    const float inv = 1.0f / ssum;

    // ---- output transpose through bufA (same swizzle), coalesced stores ----
#pragma unroll
    for (int q = 0; q < 16; ++q) {
        float4v v;
#pragma unroll
        for (int i = 0; i < 4; ++i) v[i] = vin[q * 4 + i] * inv;
        *(float4v*)&bufA[(16 * t + (q ^ sw)) * 4] = v;
    }
    __syncthreads();    // single wave: lgkm drain only
#pragma unroll
    for (int k = 0; k < 16; ++k) {
        const int p = k * 64 + t;
        float4v v = *(const float4v*)&bufA[p * 4];
        const int r  = p >> 4;
        const int jq = (p & 15) ^ (r & 7);
        *(float4v*)(gout + (uint32_t)(row0 + r) * 64u + (uint32_t)jq * 4u) = v;
    }
}

extern "C" void kernel_launch(void* const* d_in, const int* in_sizes, int n_in,
                              void* d_out, int out_size, void* d_ws, size_t ws_size,
                              hipStream_t stream) {
    const float* gin = (const float*)d_in[0];
    const float* gnz = (const float*)d_in[1];
    float* gout = (float*)d_out;
    const int nrows = in_sizes[0] / EXPERTS;   // 1,048,576
    const int grid  = nrows / 64;              // 16384 single-wave blocks
    gumbel_topk_softmax_kernel<<<grid, 64, 0, stream>>>(gin, gnz, gout);
}